// Round 5
// baseline (469.287 us; speedup 1.0000x reference)
//
#include <hip/hip_runtime.h>
#include <math.h>

constexpr int BB = 8, NN = 2048, CC = 768, HH = 12, DD = 64;
constexpr float SCALE2 = 0.18033688011112042f;   // 0.125 * log2(e)
constexpr long long BNC = (long long)BB * NN * CC;   // 12,582,912
constexpr long long WN  = 589824LL;                  // 768*768
constexpr long long XN  = BNC;                       // x element count

using bf16x8  = __attribute__((ext_vector_type(8))) __bf16;
using floatx4 = __attribute__((ext_vector_type(4))) float;
using f16x4   = __attribute__((ext_vector_type(4))) _Float16;
using f16x8   = __attribute__((ext_vector_type(8))) _Float16;

static __device__ __forceinline__ unsigned short f2bf(float x) {
  unsigned u = __builtin_bit_cast(unsigned, x);
  u += 0x7fffu + ((u >> 16) & 1u);
  return (unsigned short)(u >> 16);
}
static __device__ __forceinline__ float bf2f(unsigned short s) {
  unsigned u = ((unsigned)s) << 16;
  return __builtin_bit_cast(float, u);
}

static __device__ __forceinline__ void async_copy16(const unsigned short* g, unsigned short* l) {
  __builtin_amdgcn_global_load_lds(
      (const __attribute__((address_space(1))) unsigned int*)g,
      (__attribute__((address_space(3))) unsigned int*)l, 16, 0, 0);
}

// ---------------------------------------------------------------------------
// Convert pass: x -> bf16, wcat = concat(qw,kw,vw) bf16, owb = ow bf16,
// bcat = concat(qb,kb,vb) f32.
// ---------------------------------------------------------------------------
__global__ void convert_kernel(const float* __restrict__ x,
    const float* __restrict__ qw, const float* __restrict__ kw,
    const float* __restrict__ vw, const float* __restrict__ ow,
    const float* __restrict__ qb, const float* __restrict__ kb,
    const float* __restrict__ vb,
    unsigned short* __restrict__ xb, unsigned short* __restrict__ wcat,
    unsigned short* __restrict__ owb, float* __restrict__ bcat) {
  const long long gid = (long long)blockIdx.x * 256 + threadIdx.x;
  const long long off = gid * 4;
  if (off < XN + 4 * WN) {
    const float* s; unsigned short* d;
    if (off < XN)              { s = x  + off;                 d = xb   + off; }
    else if (off < XN + WN)    { s = qw + (off - XN);          d = wcat + (off - XN); }
    else if (off < XN + 2*WN)  { s = kw + (off - XN - WN);     d = wcat + (off - XN); }
    else if (off < XN + 3*WN)  { s = vw + (off - XN - 2*WN);   d = wcat + (off - XN); }
    else                       { s = ow + (off - XN - 3*WN);   d = owb  + (off - XN - 3*WN); }
    floatx4 v = *(const floatx4*)s;
    union { unsigned short us[4]; unsigned long long u; } pk;
    pk.us[0] = f2bf(v.x); pk.us[1] = f2bf(v.y); pk.us[2] = f2bf(v.z); pk.us[3] = f2bf(v.w);
    *(unsigned long long*)d = pk.u;
  } else {
    long long r = gid - (XN + 4 * WN) / 4;
    if (r < 576) {
      long long o2 = r * 4;
      const float* s = (o2 < 768) ? qb + o2 : (o2 < 1536) ? kb + (o2 - 768) : vb + (o2 - 1536);
      *(floatx4*)(bcat + o2) = *(const floatx4*)s;
    }
  }
}

// ---------------------------------------------------------------------------
// m97-style GEMM with XOR-swizzled LDS (chunk c of row r holds global chunk
// c ^ (r&7)): staging fetches permuted 16B chunks; frag reads XOR with ml&7
// -> 2-way bank access (free) instead of 16-way.
// OUT_MODE 0: QKV split (y:0-5 Q bf16, 6-11 K bf16, 12-17 V^T f16 PERMUTED
// per 128-key chunk: pos = quad*32 + nt*4 + r). OUT_MODE 1: f32 out.
// ---------------------------------------------------------------------------
template<int OUT_MODE>
__global__ __launch_bounds__(256, 3)
void gemm_m97(const unsigned short* __restrict__ A,
              const unsigned short* __restrict__ Bw,
              const float* __restrict__ bias,
              unsigned short* __restrict__ Qo,
              unsigned short* __restrict__ Ko,
              unsigned short* __restrict__ Vo,
              float* __restrict__ Fo) {
  __shared__ __align__(16) unsigned short As[128 * 64];
  __shared__ __align__(16) unsigned short Bs[128 * 64];
  const int t    = threadIdx.x;
  const int lane = t & 63;
  const int wv   = t >> 6;
  const int q    = lane >> 4;
  const int ml   = lane & 15;
  const int wm   = wv >> 1, wn = wv & 1;
  const int m0   = blockIdx.x * 128;
  const int n0   = blockIdx.y * 128;
  const int scol = ((lane & 7) ^ (lane >> 3)) * 8;   // swizzled source column

  const unsigned short* Ag = A  + (size_t)(m0 + wv * 32 + (lane >> 3)) * CC + scol;
  const unsigned short* Bg = Bw + (size_t)(n0 + wv * 32 + (lane >> 3)) * CC + scol;
  unsigned short* Al = As + (wv * 32) * 64;
  unsigned short* Bl = Bs + (wv * 32) * 64;

  floatx4 acc[4][4] = {};

  for (int k0 = 0; k0 < CC; k0 += 64) {
    #pragma unroll
    for (int i = 0; i < 4; ++i) {
      async_copy16(Ag + (size_t)i * 8 * CC + k0, Al + i * 8 * 64);
      async_copy16(Bg + (size_t)i * 8 * CC + k0, Bl + i * 8 * 64);
    }
    __syncthreads();
    #pragma unroll
    for (int kk = 0; kk < 2; ++kk) {
      bf16x8 af[4], bg[4];
      #pragma unroll
      for (int mt = 0; mt < 4; ++mt) {
        const int ch = ((kk * 4 + q) ^ (ml & 7)) * 8;
        af[mt] = *(const bf16x8*)&As[(wm * 64 + mt * 16 + ml) * 64 + ch];
      }
      #pragma unroll
      for (int nt = 0; nt < 4; ++nt) {
        const int ch = ((kk * 4 + q) ^ (ml & 7)) * 8;
        bg[nt] = *(const bf16x8*)&Bs[(wn * 64 + nt * 16 + ml) * 64 + ch];
      }
      #pragma unroll
      for (int mt = 0; mt < 4; ++mt)
        #pragma unroll
        for (int nt = 0; nt < 4; ++nt)
          acc[mt][nt] = __builtin_amdgcn_mfma_f32_16x16x32_bf16(af[mt], bg[nt], acc[mt][nt], 0, 0, 0);
    }
    __syncthreads();
  }

  #pragma unroll
  for (int nt = 0; nt < 4; ++nt) {
    const int col = n0 + wn * 64 + nt * 16 + ml;
    const float bv = bias[col];
    #pragma unroll
    for (int mt = 0; mt < 4; ++mt) {
      const int mbase = m0 + wm * 64 + mt * 16 + q * 4;
      if (OUT_MODE == 1) {
        #pragma unroll
        for (int r = 0; r < 4; ++r)
          Fo[(size_t)(mbase + r) * CC + col] = acc[mt][nt][r] + bv;
      } else {
        const int region = blockIdx.y / 6;            // 0=Q,1=K,2=V
        const int lc = col - region * CC;
        const int h = lc >> 6, hd = lc & 63;
        const int bidx = mbase >> 11;
        if (region == 2) {
          // permuted V^T f16: n' = (n&~127) + quad_*32 + nt_*4 + r
          const int nloc  = mbase & (NN - 1);
          const int pbase = (nloc & ~127) + (((nloc >> 2) & 3) << 5) + (((nloc >> 4) & 7) << 2);
          union { _Float16 h4[4]; unsigned long long u; } pk;
          #pragma unroll
          for (int r = 0; r < 4; ++r) pk.h4[r] = (_Float16)(acc[mt][nt][r] + bv);
          *(unsigned long long*)&Vo[((size_t)(bidx * HH + h) * DD + hd) * NN + pbase] = pk.u;
        } else {
          const int n = mbase & (NN - 1);
          unsigned short* o = (region == 0) ? Qo : Ko;
          #pragma unroll
          for (int r = 0; r < 4; ++r)
            o[((size_t)(bidx * HH + h) * NN + n + r) * DD + hd] = f2bf(acc[mt][nt][r] + bv);
        }
      }
    }
  }
}

// ---------------------------------------------------------------------------
// Flash attention v4: S^T formulation + XOR-swizzled K/V LDS.
//  S^T = mfma(A=K-frag, B=Q-frag) -> P^T lives in registers in exactly the
//  B-operand layout of a K=16 MFMA; O^T += mfma_16x16x16_f16(V-frag, P^T).
//  Row sums via ones-A-frag MFMA. K & V staged via global_load_lds with
//  chunk-XOR swizzle (2-way banks on all frag reads).
// ---------------------------------------------------------------------------
__global__ __launch_bounds__(256, 4)
void attn_kernel(const unsigned short* __restrict__ Qp,
                 const unsigned short* __restrict__ Kp,
                 const unsigned short* __restrict__ Vt,   // f16, permuted
                 const float* __restrict__ sz,
                 unsigned short* __restrict__ attn_out) {
  __shared__ __align__(16) unsigned short Ks[128 * 64];   // bf16, swizzled
  __shared__ __align__(16) unsigned short Vs[64 * 128];   // f16, permuted+swizzled
  __shared__ float biasS[128];

  const int t    = threadIdx.x;
  const int lane = t & 63;
  const int wv   = t >> 6;
  const int q    = lane >> 4;
  const int ml   = lane & 15;
  const int bh   = blockIdx.x >> 4;       // 0..95
  const int qt   = blockIdx.x & 15;
  const int b    = bh / HH, h = bh % HH;
  const int qbase = qt * 128 + wv * 32;

  // Q B-frags: B[k=d=q*8+i][n=query=ml]
  bf16x8 qf[2][2];
  #pragma unroll
  for (int mq = 0; mq < 2; ++mq)
    #pragma unroll
    for (int kt = 0; kt < 2; ++kt)
      qf[mq][kt] = *(const bf16x8*)(Qp + ((size_t)bh * NN + qbase + mq * 16 + ml) * DD + kt * 32 + q * 8);

  floatx4 O[2][4] = {};     // O^T: row d = dt*16+quad*4+r, col query = mq*16+ml
  floatx4 Osum[2] = {};
  f16x4 vone = {(_Float16)1.f, (_Float16)1.f, (_Float16)1.f, (_Float16)1.f};

  const int kswz = ((lane & 7) ^ (lane >> 3)) * 8;        // K staging column
  const int vswz = ((lane & 15) ^ (lane >> 4)) * 8;       // V staging column (i even)
  const unsigned short* Kg = Kp + ((size_t)bh * NN + wv * 32 + (lane >> 3)) * DD + kswz;
  const unsigned short* Vg = Vt + ((size_t)bh * DD + wv * 16 + (lane >> 4)) * NN;
  unsigned short* Kl = Ks + (wv * 32) * 64;
  unsigned short* Vl = Vs + (wv * 16) * 128;

  for (int j0 = 0; j0 < NN; j0 += 128) {
    // ---- async stage K [128][64] and V^T-permuted [64][128], swizzled ----
    #pragma unroll
    for (int i = 0; i < 4; ++i) {
      async_copy16(Kg + (size_t)(j0 + i * 8) * DD, Kl + i * 8 * 64);
      async_copy16(Vg + (size_t)(i * 4) * NN + j0 + (vswz ^ ((i & 1) << 5)), Vl + i * 4 * 128);
    }
    if (t < 128) biasS[t] = log2f(sz[(size_t)b * NN + j0 + t]);
    __syncthreads();

    // bias per key row: key-in-tile = nt*16 + quad*4 + r
    floatx4 bf[8];
    #pragma unroll
    for (int nt = 0; nt < 8; ++nt)
      bf[nt] = *(const floatx4*)&biasS[nt * 16 + q * 4];

    // ---- S^T = K Q^T (swizzled chunk reads) ----
    floatx4 S[2][8];
    #pragma unroll
    for (int nt = 0; nt < 8; ++nt) {
      const int ch0 = (q ^ (ml & 7)) * 8;
      const int ch1 = ((4 + q) ^ (ml & 7)) * 8;
      bf16x8 kf0 = *(const bf16x8*)&Ks[(nt * 16 + ml) * 64 + ch0];
      bf16x8 kf1 = *(const bf16x8*)&Ks[(nt * 16 + ml) * 64 + ch1];
      #pragma unroll
      for (int mq = 0; mq < 2; ++mq) {
        floatx4 a = {0.f, 0.f, 0.f, 0.f};
        a = __builtin_amdgcn_mfma_f32_16x16x32_bf16(kf0, qf[mq][0], a, 0, 0, 0);
        a = __builtin_amdgcn_mfma_f32_16x16x32_bf16(kf1, qf[mq][1], a, 0, 0, 0);
        S[mq][nt] = a;
      }
    }

    // ---- p = exp2(s*SCALE2 + log2(size_k)); P^T straight into f16 B-frags ----
    f16x4 pf[2][8];
    #pragma unroll
    for (int mq = 0; mq < 2; ++mq)
      #pragma unroll
      for (int nt = 0; nt < 8; ++nt)
        #pragma unroll
        for (int r = 0; r < 4; ++r)
          pf[mq][nt][r] = (_Float16)__builtin_amdgcn_exp2f(fmaf(S[mq][nt][r], SCALE2, bf[nt][r]));

    // ---- O^T += V^T P^T (K=16 f16 MFMA); Osum += 1 * P^T ----
    #pragma unroll
    for (int dt = 0; dt < 4; ++dt) {
      #pragma unroll
      for (int tt = 0; tt < 4; ++tt) {
        const int ch = ((q * 4 + tt) ^ (ml & 7)) * 8;
        f16x8 vv = *(const f16x8*)&Vs[(dt * 16 + ml) * 128 + ch];
        f16x4 va = __builtin_shufflevector(vv, vv, 0, 1, 2, 3);
        f16x4 vb = __builtin_shufflevector(vv, vv, 4, 5, 6, 7);
        #pragma unroll
        for (int mq = 0; mq < 2; ++mq) {
          O[mq][dt] = __builtin_amdgcn_mfma_f32_16x16x16f16(va, pf[mq][2 * tt],     O[mq][dt], 0, 0, 0);
          O[mq][dt] = __builtin_amdgcn_mfma_f32_16x16x16f16(vb, pf[mq][2 * tt + 1], O[mq][dt], 0, 0, 0);
        }
      }
    }
    #pragma unroll
    for (int mq = 0; mq < 2; ++mq)
      #pragma unroll
      for (int nt = 0; nt < 8; ++nt)
        Osum[mq] = __builtin_amdgcn_mfma_f32_16x16x16f16(vone, pf[mq][nt], Osum[mq], 0, 0, 0);

    __syncthreads();   // all K/V LDS reads done before next tile's staging
  }

  // ---- epilogue: lane owns query = qbase+mq*16+ml, d = dt*16+quad*4+r ----
  #pragma unroll
  for (int mq = 0; mq < 2; ++mq) {
    const float linv = 1.0f / Osum[mq][0];
    const int query = qbase + mq * 16 + ml;
    #pragma unroll
    for (int dt = 0; dt < 4; ++dt) {
      union { unsigned short us[4]; unsigned long long u; } pk;
      #pragma unroll
      for (int r = 0; r < 4; ++r) pk.us[r] = f2bf(O[mq][dt][r] * linv);
      *(unsigned long long*)&attn_out[((size_t)b * NN + query) * CC + h * DD + dt * 16 + q * 4] = pk.u;
    }
  }
}

// ---------------------------------------------------------------------------
// k_mean[b,n,hd] = (1/H) sum_h K[b,h,n,hd]
// ---------------------------------------------------------------------------
__global__ void kmean_kernel(const unsigned short* __restrict__ Kp, float* __restrict__ o) {
  int idx = blockIdx.x * 256 + threadIdx.x;
  int hd = idx & 63;
  int n  = (idx >> 6) & (NN - 1);
  int b  = idx >> 17;
  float s = 0.f;
  #pragma unroll
  for (int h = 0; h < HH; ++h)
    s += bf2f(Kp[(((size_t)b * HH + h) * NN + n) * DD + hd]);
  o[idx] = s * (1.0f / 12.0f);
}

extern "C" void kernel_launch(void* const* d_in, const int* in_sizes, int n_in,
                              void* d_out, int out_size, void* d_ws, size_t ws_size,
                              hipStream_t stream) {
  const float* x   = (const float*)d_in[0];
  const float* sz  = (const float*)d_in[1];
  const float* q_w = (const float*)d_in[2];
  const float* q_b = (const float*)d_in[3];
  const float* k_w = (const float*)d_in[4];
  const float* k_b = (const float*)d_in[5];
  const float* v_w = (const float*)d_in[6];
  const float* v_b = (const float*)d_in[7];
  const float* o_w = (const float*)d_in[8];
  const float* o_b = (const float*)d_in[9];

  float* out0  = (float*)d_out;              // [B,N,C] f32
  float* outKm = out0 + (size_t)BNC;         // [B,N,HD] f32

  unsigned short* xb   = (unsigned short*)d_ws;              // bf16 x / later Aw
  unsigned short* wcat = xb + XN;                            // bf16 [2304][768]
  unsigned short* owb  = wcat + 3 * WN;                      // bf16 [768][768]
  float*          bcat = (float*)(owb + WN);                 // f32 [2304]
  unsigned short* Qw   = (unsigned short*)(bcat + 2304);     // bf16 [B,H,N,64]
  unsigned short* Kw   = Qw + BNC;                           // bf16 [B,H,N,64]
  unsigned short* Vtw  = Kw + BNC;                           // f16  [B,H,64,N] permuted
  unsigned short* Aw   = xb;                                 // alias

  dim3 tb(256, 1, 1);
  convert_kernel<<<dim3(14595), tb, 0, stream>>>(x, q_w, k_w, v_w, o_w, q_b, k_b, v_b,
                                                 xb, wcat, owb, bcat);
  gemm_m97<0><<<dim3(128, 18), tb, 0, stream>>>(xb, wcat, bcat, Qw, Kw, Vtw, nullptr);
  attn_kernel<<<dim3(BB * HH * 16), tb, 0, stream>>>(Qw, Kw, Vtw, sz, Aw);
  gemm_m97<1><<<dim3(128, 6), tb, 0, stream>>>(Aw, owb, o_b, nullptr, nullptr, nullptr, out0);
  kmean_kernel<<<dim3(4096), tb, 0, stream>>>(Kw, outKm);
}

// Round 6
// 368.859 us; speedup vs baseline: 1.2723x; 1.2723x over previous
//
#include <hip/hip_runtime.h>
#include <math.h>

constexpr int BB = 8, NN = 2048, CC = 768, HH = 12, DD = 64;
constexpr float SCALE2 = 0.18033688011112042f;   // 0.125 * log2(e)
constexpr long long BNC = (long long)BB * NN * CC;   // 12,582,912
constexpr long long WN  = 589824LL;                  // 768*768
constexpr long long XN  = BNC;                       // x element count

using bf16x8  = __attribute__((ext_vector_type(8))) __bf16;
using floatx4 = __attribute__((ext_vector_type(4))) float;
using f16x4   = __attribute__((ext_vector_type(4))) _Float16;
using f16x8   = __attribute__((ext_vector_type(8))) _Float16;

static __device__ __forceinline__ unsigned short f2bf(float x) {
  unsigned u = __builtin_bit_cast(unsigned, x);
  u += 0x7fffu + ((u >> 16) & 1u);
  return (unsigned short)(u >> 16);
}
static __device__ __forceinline__ float bf2f(unsigned short s) {
  unsigned u = ((unsigned)s) << 16;
  return __builtin_bit_cast(float, u);
}

static __device__ __forceinline__ void async_copy16(const unsigned short* g, unsigned short* l) {
  __builtin_amdgcn_global_load_lds(
      (const __attribute__((address_space(1))) unsigned int*)g,
      (__attribute__((address_space(3))) unsigned int*)l, 16, 0, 0);
}

// ---------------------------------------------------------------------------
// Convert pass: x -> bf16, wcat = concat(qw,kw,vw) bf16, owb = ow bf16,
// bcat = concat(qb,kb,vb) f32.
// ---------------------------------------------------------------------------
__global__ void convert_kernel(const float* __restrict__ x,
    const float* __restrict__ qw, const float* __restrict__ kw,
    const float* __restrict__ vw, const float* __restrict__ ow,
    const float* __restrict__ qb, const float* __restrict__ kb,
    const float* __restrict__ vb,
    unsigned short* __restrict__ xb, unsigned short* __restrict__ wcat,
    unsigned short* __restrict__ owb, float* __restrict__ bcat) {
  const long long gid = (long long)blockIdx.x * 256 + threadIdx.x;
  const long long off = gid * 4;
  if (off < XN + 4 * WN) {
    const float* s; unsigned short* d;
    if (off < XN)              { s = x  + off;                 d = xb   + off; }
    else if (off < XN + WN)    { s = qw + (off - XN);          d = wcat + (off - XN); }
    else if (off < XN + 2*WN)  { s = kw + (off - XN - WN);     d = wcat + (off - XN); }
    else if (off < XN + 3*WN)  { s = vw + (off - XN - 2*WN);   d = wcat + (off - XN); }
    else                       { s = ow + (off - XN - 3*WN);   d = owb  + (off - XN - 3*WN); }
    floatx4 v = *(const floatx4*)s;
    union { unsigned short us[4]; unsigned long long u; } pk;
    pk.us[0] = f2bf(v.x); pk.us[1] = f2bf(v.y); pk.us[2] = f2bf(v.z); pk.us[3] = f2bf(v.w);
    *(unsigned long long*)d = pk.u;
  } else {
    long long r = gid - (XN + 4 * WN) / 4;
    if (r < 576) {
      long long o2 = r * 4;
      const float* s = (o2 < 768) ? qb + o2 : (o2 < 1536) ? kb + (o2 - 768) : vb + (o2 - 1536);
      *(floatx4*)(bcat + o2) = *(const floatx4*)s;
    }
  }
}

// ---------------------------------------------------------------------------
// m97-style GEMM with XOR-swizzled LDS (chunk c of row r holds global chunk
// c ^ (r&7)): staging fetches permuted 16B chunks; frag reads XOR with ml&7
// -> 2-way bank access (free) instead of 16-way.
// OUT_MODE 0: QKV split (y:0-5 Q bf16, 6-11 K bf16, 12-17 V^T f16 PERMUTED
// per 128-key chunk: pos = quad*32 + nt*4 + r). OUT_MODE 1: f32 out.
// ---------------------------------------------------------------------------
template<int OUT_MODE>
__global__ __launch_bounds__(256, 3)
void gemm_m97(const unsigned short* __restrict__ A,
              const unsigned short* __restrict__ Bw,
              const float* __restrict__ bias,
              unsigned short* __restrict__ Qo,
              unsigned short* __restrict__ Ko,
              unsigned short* __restrict__ Vo,
              float* __restrict__ Fo) {
  __shared__ __align__(16) unsigned short As[128 * 64];
  __shared__ __align__(16) unsigned short Bs[128 * 64];
  const int t    = threadIdx.x;
  const int lane = t & 63;
  const int wv   = t >> 6;
  const int q    = lane >> 4;
  const int ml   = lane & 15;
  const int wm   = wv >> 1, wn = wv & 1;
  const int m0   = blockIdx.x * 128;
  const int n0   = blockIdx.y * 128;
  const int scol = ((lane & 7) ^ (lane >> 3)) * 8;   // swizzled source column

  const unsigned short* Ag = A  + (size_t)(m0 + wv * 32 + (lane >> 3)) * CC + scol;
  const unsigned short* Bg = Bw + (size_t)(n0 + wv * 32 + (lane >> 3)) * CC + scol;
  unsigned short* Al = As + (wv * 32) * 64;
  unsigned short* Bl = Bs + (wv * 32) * 64;

  floatx4 acc[4][4] = {};

  for (int k0 = 0; k0 < CC; k0 += 64) {
    #pragma unroll
    for (int i = 0; i < 4; ++i) {
      async_copy16(Ag + (size_t)i * 8 * CC + k0, Al + i * 8 * 64);
      async_copy16(Bg + (size_t)i * 8 * CC + k0, Bl + i * 8 * 64);
    }
    __syncthreads();
    #pragma unroll
    for (int kk = 0; kk < 2; ++kk) {
      bf16x8 af[4], bg[4];
      #pragma unroll
      for (int mt = 0; mt < 4; ++mt) {
        const int ch = ((kk * 4 + q) ^ (ml & 7)) * 8;
        af[mt] = *(const bf16x8*)&As[(wm * 64 + mt * 16 + ml) * 64 + ch];
      }
      #pragma unroll
      for (int nt = 0; nt < 4; ++nt) {
        const int ch = ((kk * 4 + q) ^ (ml & 7)) * 8;
        bg[nt] = *(const bf16x8*)&Bs[(wn * 64 + nt * 16 + ml) * 64 + ch];
      }
      #pragma unroll
      for (int mt = 0; mt < 4; ++mt)
        #pragma unroll
        for (int nt = 0; nt < 4; ++nt)
          acc[mt][nt] = __builtin_amdgcn_mfma_f32_16x16x32_bf16(af[mt], bg[nt], acc[mt][nt], 0, 0, 0);
    }
    __syncthreads();
  }

  #pragma unroll
  for (int nt = 0; nt < 4; ++nt) {
    const int col = n0 + wn * 64 + nt * 16 + ml;
    const float bv = bias[col];
    #pragma unroll
    for (int mt = 0; mt < 4; ++mt) {
      const int mbase = m0 + wm * 64 + mt * 16 + q * 4;
      if (OUT_MODE == 1) {
        #pragma unroll
        for (int r = 0; r < 4; ++r)
          Fo[(size_t)(mbase + r) * CC + col] = acc[mt][nt][r] + bv;
      } else {
        const int region = blockIdx.y / 6;            // 0=Q,1=K,2=V
        const int lc = col - region * CC;
        const int h = lc >> 6, hd = lc & 63;
        const int bidx = mbase >> 11;
        if (region == 2) {
          // permuted V^T f16: n' = (n&~127) + quad_*32 + nt_*4 + r
          const int nloc  = mbase & (NN - 1);
          const int pbase = (nloc & ~127) + (((nloc >> 2) & 3) << 5) + (((nloc >> 4) & 7) << 2);
          union { _Float16 h4[4]; unsigned long long u; } pk;
          #pragma unroll
          for (int r = 0; r < 4; ++r) pk.h4[r] = (_Float16)(acc[mt][nt][r] + bv);
          *(unsigned long long*)&Vo[((size_t)(bidx * HH + h) * DD + hd) * NN + pbase] = pk.u;
        } else {
          const int n = mbase & (NN - 1);
          unsigned short* o = (region == 0) ? Qo : Ko;
          #pragma unroll
          for (int r = 0; r < 4; ++r)
            o[((size_t)(bidx * HH + h) * NN + n + r) * DD + hd] = f2bf(acc[mt][nt][r] + bv);
        }
      }
    }
  }
}

// ---------------------------------------------------------------------------
// Flash attention v5: S^T formulation + XOR-swizzled K/V LDS.
// launch_bounds(256,3): (256,4) capped VGPR at 128 -> allocator spilled the
// register-resident S/P/O state to scratch (WRITE_SIZE 27->505 MB, R5).
// 3 blocks/CU keeps 84 VGPR, zero spills.
// ---------------------------------------------------------------------------
__global__ __launch_bounds__(256, 3)
void attn_kernel(const unsigned short* __restrict__ Qp,
                 const unsigned short* __restrict__ Kp,
                 const unsigned short* __restrict__ Vt,   // f16, permuted
                 const float* __restrict__ sz,
                 unsigned short* __restrict__ attn_out) {
  __shared__ __align__(16) unsigned short Ks[128 * 64];   // bf16, swizzled
  __shared__ __align__(16) unsigned short Vs[64 * 128];   // f16, permuted+swizzled
  __shared__ float biasS[128];

  const int t    = threadIdx.x;
  const int lane = t & 63;
  const int wv   = t >> 6;
  const int q    = lane >> 4;
  const int ml   = lane & 15;
  const int bh   = blockIdx.x >> 4;       // 0..95
  const int qt   = blockIdx.x & 15;
  const int b    = bh / HH, h = bh % HH;
  const int qbase = qt * 128 + wv * 32;

  // Q B-frags: B[k=d=q*8+i][n=query=ml]
  bf16x8 qf[2][2];
  #pragma unroll
  for (int mq = 0; mq < 2; ++mq)
    #pragma unroll
    for (int kt = 0; kt < 2; ++kt)
      qf[mq][kt] = *(const bf16x8*)(Qp + ((size_t)bh * NN + qbase + mq * 16 + ml) * DD + kt * 32 + q * 8);

  floatx4 O[2][4] = {};     // O^T: row d = dt*16+quad*4+r, col query = mq*16+ml
  floatx4 Osum[2] = {};
  f16x4 vone = {(_Float16)1.f, (_Float16)1.f, (_Float16)1.f, (_Float16)1.f};

  const int kswz = ((lane & 7) ^ (lane >> 3)) * 8;        // K staging column
  const int vswz = ((lane & 15) ^ (lane >> 4)) * 8;       // V staging column (i even)
  const unsigned short* Kg = Kp + ((size_t)bh * NN + wv * 32 + (lane >> 3)) * DD + kswz;
  const unsigned short* Vg = Vt + ((size_t)bh * DD + wv * 16 + (lane >> 4)) * NN;
  unsigned short* Kl = Ks + (wv * 32) * 64;
  unsigned short* Vl = Vs + (wv * 16) * 128;

  for (int j0 = 0; j0 < NN; j0 += 128) {
    // ---- async stage K [128][64] and V^T-permuted [64][128], swizzled ----
    #pragma unroll
    for (int i = 0; i < 4; ++i) {
      async_copy16(Kg + (size_t)(j0 + i * 8) * DD, Kl + i * 8 * 64);
      async_copy16(Vg + (size_t)(i * 4) * NN + j0 + (vswz ^ ((i & 1) << 5)), Vl + i * 4 * 128);
    }
    if (t < 128) biasS[t] = log2f(sz[(size_t)b * NN + j0 + t]);
    __syncthreads();

    // bias per key row: key-in-tile = nt*16 + quad*4 + r
    floatx4 bf[8];
    #pragma unroll
    for (int nt = 0; nt < 8; ++nt)
      bf[nt] = *(const floatx4*)&biasS[nt * 16 + q * 4];

    // ---- S^T = K Q^T (swizzled chunk reads) ----
    floatx4 S[2][8];
    #pragma unroll
    for (int nt = 0; nt < 8; ++nt) {
      const int ch0 = (q ^ (ml & 7)) * 8;
      const int ch1 = ((4 + q) ^ (ml & 7)) * 8;
      bf16x8 kf0 = *(const bf16x8*)&Ks[(nt * 16 + ml) * 64 + ch0];
      bf16x8 kf1 = *(const bf16x8*)&Ks[(nt * 16 + ml) * 64 + ch1];
      #pragma unroll
      for (int mq = 0; mq < 2; ++mq) {
        floatx4 a = {0.f, 0.f, 0.f, 0.f};
        a = __builtin_amdgcn_mfma_f32_16x16x32_bf16(kf0, qf[mq][0], a, 0, 0, 0);
        a = __builtin_amdgcn_mfma_f32_16x16x32_bf16(kf1, qf[mq][1], a, 0, 0, 0);
        S[mq][nt] = a;
      }
    }

    // ---- p = exp2(s*SCALE2 + log2(size_k)); P^T straight into f16 B-frags ----
    f16x4 pf[2][8];
    #pragma unroll
    for (int mq = 0; mq < 2; ++mq)
      #pragma unroll
      for (int nt = 0; nt < 8; ++nt)
        #pragma unroll
        for (int r = 0; r < 4; ++r)
          pf[mq][nt][r] = (_Float16)__builtin_amdgcn_exp2f(fmaf(S[mq][nt][r], SCALE2, bf[nt][r]));

    // ---- O^T += V^T P^T (K=16 f16 MFMA); Osum += 1 * P^T ----
    #pragma unroll
    for (int dt = 0; dt < 4; ++dt) {
      #pragma unroll
      for (int tt = 0; tt < 4; ++tt) {
        const int ch = ((q * 4 + tt) ^ (ml & 7)) * 8;
        f16x8 vv = *(const f16x8*)&Vs[(dt * 16 + ml) * 128 + ch];
        f16x4 va = __builtin_shufflevector(vv, vv, 0, 1, 2, 3);
        f16x4 vb = __builtin_shufflevector(vv, vv, 4, 5, 6, 7);
        #pragma unroll
        for (int mq = 0; mq < 2; ++mq) {
          O[mq][dt] = __builtin_amdgcn_mfma_f32_16x16x16f16(va, pf[mq][2 * tt],     O[mq][dt], 0, 0, 0);
          O[mq][dt] = __builtin_amdgcn_mfma_f32_16x16x16f16(vb, pf[mq][2 * tt + 1], O[mq][dt], 0, 0, 0);
        }
      }
    }
    #pragma unroll
    for (int mq = 0; mq < 2; ++mq)
      #pragma unroll
      for (int nt = 0; nt < 8; ++nt)
        Osum[mq] = __builtin_amdgcn_mfma_f32_16x16x16f16(vone, pf[mq][nt], Osum[mq], 0, 0, 0);

    __syncthreads();   // all K/V LDS reads done before next tile's staging
  }

  // ---- epilogue: lane owns query = qbase+mq*16+ml, d = dt*16+quad*4+r ----
  #pragma unroll
  for (int mq = 0; mq < 2; ++mq) {
    const float linv = 1.0f / Osum[mq][0];
    const int query = qbase + mq * 16 + ml;
    #pragma unroll
    for (int dt = 0; dt < 4; ++dt) {
      union { unsigned short us[4]; unsigned long long u; } pk;
      #pragma unroll
      for (int r = 0; r < 4; ++r) pk.us[r] = f2bf(O[mq][dt][r] * linv);
      *(unsigned long long*)&attn_out[((size_t)b * NN + query) * CC + h * DD + dt * 16 + q * 4] = pk.u;
    }
  }
}

// ---------------------------------------------------------------------------
// k_mean[b,n,hd] = (1/H) sum_h K[b,h,n,hd]
// ---------------------------------------------------------------------------
__global__ void kmean_kernel(const unsigned short* __restrict__ Kp, float* __restrict__ o) {
  int idx = blockIdx.x * 256 + threadIdx.x;
  int hd = idx & 63;
  int n  = (idx >> 6) & (NN - 1);
  int b  = idx >> 17;
  float s = 0.f;
  #pragma unroll
  for (int h = 0; h < HH; ++h)
    s += bf2f(Kp[(((size_t)b * HH + h) * NN + n) * DD + hd]);
  o[idx] = s * (1.0f / 12.0f);
}

extern "C" void kernel_launch(void* const* d_in, const int* in_sizes, int n_in,
                              void* d_out, int out_size, void* d_ws, size_t ws_size,
                              hipStream_t stream) {
  const float* x   = (const float*)d_in[0];
  const float* sz  = (const float*)d_in[1];
  const float* q_w = (const float*)d_in[2];
  const float* q_b = (const float*)d_in[3];
  const float* k_w = (const float*)d_in[4];
  const float* k_b = (const float*)d_in[5];
  const float* v_w = (const float*)d_in[6];
  const float* v_b = (const float*)d_in[7];
  const float* o_w = (const float*)d_in[8];
  const float* o_b = (const float*)d_in[9];

  float* out0  = (float*)d_out;              // [B,N,C] f32
  float* outKm = out0 + (size_t)BNC;         // [B,N,HD] f32

  unsigned short* xb   = (unsigned short*)d_ws;              // bf16 x / later Aw
  unsigned short* wcat = xb + XN;                            // bf16 [2304][768]
  unsigned short* owb  = wcat + 3 * WN;                      // bf16 [768][768]
  float*          bcat = (float*)(owb + WN);                 // f32 [2304]
  unsigned short* Qw   = (unsigned short*)(bcat + 2304);     // bf16 [B,H,N,64]
  unsigned short* Kw   = Qw + BNC;                           // bf16 [B,H,N,64]
  unsigned short* Vtw  = Kw + BNC;                           // f16  [B,H,64,N] permuted
  unsigned short* Aw   = xb;                                 // alias

  dim3 tb(256, 1, 1);
  convert_kernel<<<dim3(14595), tb, 0, stream>>>(x, q_w, k_w, v_w, o_w, q_b, k_b, v_b,
                                                 xb, wcat, owb, bcat);
  gemm_m97<0><<<dim3(128, 18), tb, 0, stream>>>(xb, wcat, bcat, Qw, Kw, Vtw, nullptr);
  attn_kernel<<<dim3(BB * HH * 16), tb, 0, stream>>>(Qw, Kw, Vtw, sz, Aw);
  gemm_m97<1><<<dim3(128, 6), tb, 0, stream>>>(Aw, owb, o_b, nullptr, nullptr, nullptr, out0);
  kmean_kernel<<<dim3(4096), tb, 0, stream>>>(Kw, outKm);
}